// Round 3
// baseline (14.239 us; speedup 1.0000x reference)
//
#include <hip/hip_runtime.h>

// CenterLoss: B=1024, D=128, C=100000.
// Exact algebraic collapse of the reference:
//   out = (1/B) * sum_b clip(||x_b - centers[labels_b]||^2, 1e-12, 1e12)
//         + (C-1) * 1e-12            // B*(C-1) masked zeros, each clamped to 1e-12
// Single kernel launch + 4-byte memset node. Last-block-done reduction
// (no grid.sync, no spinning -> no co-residency assumption, deadlock-free).

#define CL_B 1024
#define CL_D 128
#define CL_C 100000
#define NBLK 64                         // partial-sum blocks
#define SPB  (CL_B / NBLK)              // 16 samples per block
#define SPW  (SPB / 4)                  // 4 samples per wave (4 waves/block)

__global__ __launch_bounds__(256) void cl_onekernel(
    const float* __restrict__ x,
    const int* __restrict__ labels,
    const float* __restrict__ centers,
    float* __restrict__ partials,       // ws[0..NBLK-1]
    unsigned int* __restrict__ counter, // ws[NBLK], memset to 0 each call
    float* __restrict__ out) {
    const int t    = threadIdx.x;       // 0..255
    const int wave = t >> 6;            // 0..3
    const int lane = t & 63;            // wave = 64 lanes on CDNA

    // Each wave handles SPW consecutive samples; lane covers 2 floats (float2).
    float acc = 0.0f;
    const int base = blockIdx.x * SPB + wave * SPW;
    #pragma unroll
    for (int i = 0; i < SPW; ++i) {
        const int b   = base + i;
        const int lab = labels[b];
        const float2 xv = reinterpret_cast<const float2*>(x + (size_t)b * CL_D)[lane];
        const float2 cv = reinterpret_cast<const float2*>(centers + (size_t)lab * CL_D)[lane];
        const float d0 = xv.x - cv.x;
        const float d1 = xv.y - cv.y;
        float s = d0 * d0 + d1 * d1;
        #pragma unroll
        for (int off = 32; off > 0; off >>= 1)
            s += __shfl_down(s, off, 64);
        if (lane == 0)                          // lane 0 holds the sample total
            acc += fminf(fmaxf(s, 1e-12f), 1e12f);   // clip per sample
    }

    __shared__ float sm[4];
    __shared__ int   is_last;
    if (lane == 0) sm[wave] = acc;
    __syncthreads();

    if (t == 0) {
        partials[blockIdx.x] = sm[0] + sm[1] + sm[2] + sm[3];
        __threadfence();                        // release partial (device scope)
        const unsigned old = atomicAdd(counter, 1u);
        is_last = (old == NBLK - 1u);
        if (is_last) __threadfence();           // acquire side
    }
    __syncthreads();

    if (is_last && wave == 0) {
        // First wave of the last block reduces the NBLK partials (fixed order
        // -> bitwise-deterministic regardless of which block runs this).
        volatile const float* vp = partials;    // bypass L1 (other blocks wrote)
        float v = vp[lane];                     // NBLK == 64
        #pragma unroll
        for (int off = 32; off > 0; off >>= 1)
            v += __shfl_down(v, off, 64);
        if (lane == 0)
            out[0] = v / (float)CL_B + (float)(CL_C - 1) * 1e-12f;
    }
}

extern "C" void kernel_launch(void* const* d_in, const int* in_sizes, int n_in,
                              void* d_out, int out_size, void* d_ws, size_t ws_size,
                              hipStream_t stream) {
    const float* x       = (const float*)d_in[0];   // [1024, 128] f32
    const int*   labels  = (const int*)d_in[1];     // [1024] int
    const float* centers = (const float*)d_in[2];   // [100000, 128] f32
    float* out = (float*)d_out;                     // [1] f32
    float* partials = (float*)d_ws;                 // NBLK floats
    unsigned int* counter = (unsigned int*)((char*)d_ws + NBLK * sizeof(float));

    // Counter must be 0 at kernel start every call (ws is poisoned once and
    // never re-poisoned; the kernel leaves it at NBLK). 4-byte memset node.
    hipMemsetAsync(counter, 0, sizeof(unsigned int), stream);
    cl_onekernel<<<NBLK, 256, 0, stream>>>(x, labels, centers, partials, counter, out);
}

// Round 4
// 9.589 us; speedup vs baseline: 1.4849x; 1.4849x over previous
//
#include <hip/hip_runtime.h>

// CenterLoss: B=1024, D=128, C=100000.
// Exact algebraic collapse of the reference:
//   out = (1/B) * sum_b clip(||x_b - centers[labels_b]||^2, 1e-12, 1e12)
//         + (C-1) * 1e-12            // B*(C-1) masked zeros, each clamped to 1e-12
// ONE kernel dispatch, no memset node. Cross-block completion via a
// __device__ module-global counter (load-time zeroed, poison-immune;
// last block resets it to 0 -> invariant across calls, deterministic).

#define CL_B 1024
#define CL_D 128
#define CL_C 100000
#define NBLK 64                         // partial-sum blocks
#define SPB  (CL_B / NBLK)              // 16 samples per block
#define SPW  (SPB / 4)                  // 4 samples per wave (4 waves/block)

__device__ unsigned int cl_counter = 0;   // arrival counter, 0 at every call start/end
__device__ float        cl_partials[NBLK];

__global__ __launch_bounds__(256) void cl_onekernel(
    const float* __restrict__ x,
    const int* __restrict__ labels,
    const float* __restrict__ centers,
    float* __restrict__ out) {
    const int t    = threadIdx.x;       // 0..255
    const int wave = t >> 6;            // 0..3
    const int lane = t & 63;            // wave = 64 lanes on CDNA

    // Each wave handles SPW consecutive samples; lane covers 2 floats (float2).
    float acc = 0.0f;
    const int base = blockIdx.x * SPB + wave * SPW;
    #pragma unroll
    for (int i = 0; i < SPW; ++i) {
        const int b   = base + i;
        const int lab = labels[b];
        const float2 xv = reinterpret_cast<const float2*>(x + (size_t)b * CL_D)[lane];
        const float2 cv = reinterpret_cast<const float2*>(centers + (size_t)lab * CL_D)[lane];
        const float d0 = xv.x - cv.x;
        const float d1 = xv.y - cv.y;
        float s = d0 * d0 + d1 * d1;
        #pragma unroll
        for (int off = 32; off > 0; off >>= 1)
            s += __shfl_down(s, off, 64);
        if (lane == 0)                          // lane 0 holds the sample total
            acc += fminf(fmaxf(s, 1e-12f), 1e12f);   // clip per sample
    }

    __shared__ float sm[4];
    __shared__ int   is_last;
    if (lane == 0) sm[wave] = acc;
    __syncthreads();

    if (t == 0) {
        cl_partials[blockIdx.x] = sm[0] + sm[1] + sm[2] + sm[3];
        __threadfence();                        // release partial (device scope)
        const unsigned old = atomicAdd(&cl_counter, 1u);
        is_last = (old == NBLK - 1u);
        if (is_last) {
            __threadfence();                    // acquire side
            // 64th (last) serialized atomic: no other block touches the
            // counter after this -> safe to reset for the next call.
            atomicExch(&cl_counter, 0u);
        }
    }
    __syncthreads();

    if (is_last && wave == 0) {
        // First wave of the last block reduces the NBLK partials (fixed order
        // -> bitwise-deterministic regardless of which block runs this).
        volatile const float* vp = cl_partials; // bypass L1 (other blocks wrote)
        float v = vp[lane];                     // NBLK == 64
        #pragma unroll
        for (int off = 32; off > 0; off >>= 1)
            v += __shfl_down(v, off, 64);
        if (lane == 0)
            out[0] = v / (float)CL_B + (float)(CL_C - 1) * 1e-12f;
    }
}

extern "C" void kernel_launch(void* const* d_in, const int* in_sizes, int n_in,
                              void* d_out, int out_size, void* d_ws, size_t ws_size,
                              hipStream_t stream) {
    const float* x       = (const float*)d_in[0];   // [1024, 128] f32
    const int*   labels  = (const int*)d_in[1];     // [1024] int
    const float* centers = (const float*)d_in[2];   // [100000, 128] f32
    float* out = (float*)d_out;                     // [1] f32
    (void)d_ws; (void)ws_size;

    cl_onekernel<<<NBLK, 256, 0, stream>>>(x, labels, centers, out);
}